// Round 1
// baseline (7436.895 us; speedup 1.0000x reference)
//
#include <hip/hip_runtime.h>

#define NV 262144          // 64^3
#define D64 64

// ---------------- Gaussian weights (13-tap, sigma=2), computed f32 like the ref ----------------
static __device__ __forceinline__ void gauss_weights(float K[13]) {
  float s = 0.f;
#pragma unroll
  for (int j = 0; j < 13; ++j) {
    float r = (float)(j - 6);
    K[j] = expf(-0.125f * r * r);   // exp(-0.5*(r/2)^2)
    s += K[j];
  }
#pragma unroll
  for (int j = 0; j < 13; ++j) K[j] = K[j] / s;
}

// ---------------- trilinear helpers (align_corners=True, border padding) ----------------
static __device__ __forceinline__ void tl_make(float gx, float gy, float gz,
                                               int sx, int sy, int sz,
                                               int id[8], float wt[8]) {
  float x = fminf(fmaxf((gx + 1.0f) * 0.5f * 63.0f, 0.0f), 63.0f);
  float y = fminf(fmaxf((gy + 1.0f) * 0.5f * 63.0f, 0.0f), 63.0f);
  float z = fminf(fmaxf((gz + 1.0f) * 0.5f * 63.0f, 0.0f), 63.0f);
  float x0f = floorf(x), y0f = floorf(y), z0f = floorf(z);
  int x0 = (int)x0f, y0 = (int)y0f, z0 = (int)z0f;
  int x1 = min(x0 + 1, 63), y1 = min(y0 + 1, 63), z1 = min(z0 + 1, 63);
  float wx = x - x0f, wy = y - y0f, wz = z - z0f;
  float ux = 1.f - wx, uy = 1.f - wy, uz = 1.f - wz;
  int X0 = x0 * sx, X1 = x1 * sx, Y0 = y0 * sy, Y1 = y1 * sy, Z0 = z0 * sz, Z1 = z1 * sz;
  id[0] = Z0 + Y0 + X0; wt[0] = uz * uy * ux;
  id[1] = Z0 + Y0 + X1; wt[1] = uz * uy * wx;
  id[2] = Z0 + Y1 + X0; wt[2] = uz * wy * ux;
  id[3] = Z0 + Y1 + X1; wt[3] = uz * wy * wx;
  id[4] = Z1 + Y0 + X0; wt[4] = wz * uy * ux;
  id[5] = Z1 + Y0 + X1; wt[5] = wz * uy * wx;
  id[6] = Z1 + Y1 + X0; wt[6] = wz * wy * ux;
  id[7] = Z1 + Y1 + X1; wt[7] = wz * wy * wx;
}

static __device__ __forceinline__ float tl_apply(const float* __restrict__ img,
                                                 const int id[8], const float wt[8]) {
  float s = 0.f;
#pragma unroll
  for (int k = 0; k < 8; ++k) s = fmaf(wt[k], img[id[k]], s);
  return s;
}

// ---------------- init ----------------
__global__ void init_kernel(const float* __restrict__ src, const float* __restrict__ z0,
                            float* __restrict__ residual, float* __restrict__ image,
                            float* __restrict__ rd0, float* __restrict__ phi0,
                            float* __restrict__ outRes0) {
  int idx = blockIdx.x * 256 + threadIdx.x;
  int d = idx >> 12, h = (idx >> 6) & 63, w = idx & 63;
  float z = z0[idx];
  residual[idx] = z;
  outRes0[idx] = z;
  image[idx] = src[idx];
  rd0[idx] = 0.f;
  const float step = 2.0f / 63.0f;
  phi0[idx] = -1.f + w * step;            // phiX[d,h,w] = xs[w]
  phi0[NV + idx] = -1.f + h * step;       // phiY = ys[h]
  phi0[2 * NV + idx] = -1.f + d * step;   // phiZ = zs[d]
}

// ---------------- spatial gradient (central diff, replicate pad) ----------------
__global__ void grad_kernel(const float* __restrict__ img, float* __restrict__ gout) {
  int idx = blockIdx.x * 256 + threadIdx.x;
  int d = idx >> 12, h = (idx >> 6) & 63, w = idx & 63;
  int wp = min(w + 1, 63), wm = max(w - 1, 0);
  int hp = min(h + 1, 63), hm = max(h - 1, 0);
  int dp = min(d + 1, 63), dm = max(d - 1, 0);
  int bd = d << 12, bh = h << 6;
  gout[idx]          = 0.5f * (img[bd + bh + wp] - img[bd + bh + wm]);
  gout[NV + idx]     = 0.5f * (img[bd + (hp << 6) + w] - img[bd + (hm << 6) + w]);
  gout[2 * NV + idx] = 0.5f * (img[(dp << 12) + bh + w] - img[(dm << 12) + bh + w]);
}

// ---------------- Gaussian smoothing passes ----------------
// pass 1 along D, fused with s = -residual * g
__global__ void smooth_d_fused(const float* __restrict__ residual, const float* __restrict__ g,
                               float* __restrict__ out) {
  int idx = blockIdx.x * 256 + threadIdx.x;
  int c = blockIdx.y;
  int d = idx >> 12;
  float K[13]; gauss_weights(K);
  const float* gc = g + (size_t)c * NV;
  float acc = 0.f;
#pragma unroll
  for (int j = 0; j < 13; ++j) {
    int dd = d + j - 6;
    if ((unsigned)dd < 64u) {
      int o = idx + ((j - 6) << 12);
      acc = fmaf(K[j], -residual[o] * gc[o], acc);
    }
  }
  out[(size_t)c * NV + idx] = acc;
}

template <int SHIFT>
__global__ void smooth_axis(const float* __restrict__ in, float* __restrict__ out) {
  int idx = blockIdx.x * 256 + threadIdx.x;
  int c = blockIdx.y;
  int pos = (idx >> SHIFT) & 63;
  float K[13]; gauss_weights(K);
  const float* ic = in + (size_t)c * NV;
  float acc = 0.f;
#pragma unroll
  for (int j = 0; j < 13; ++j) {
    int pp = pos + j - 6;
    if ((unsigned)pp < 64u) acc = fmaf(K[j], ic[idx + ((j - 6) << SHIFT)], acc);
  }
  out[(size_t)c * NV + idx] = acc;
}

// ---------------- field output + deformation buffer ----------------
// thread at (p,q,r): reads v[c, r, q, p]; writes fields[(p,q,r),c] and def(p,q,r)
__global__ void field_def_kernel(const float* __restrict__ v, float* __restrict__ fout,
                                 float* __restrict__ dx, float* __restrict__ dy,
                                 float* __restrict__ dz) {
  int idx = blockIdx.x * 256 + threadIdx.x;
  int p = idx >> 12, q = (idx >> 6) & 63, r = idx & 63;
  int tidx = (r << 12) + (q << 6) + p;
  float v0 = v[tidx], v1 = v[NV + tidx], v2 = v[2 * NV + tidx];
  fout[idx * 3 + 0] = v0;
  fout[idx * 3 + 1] = v1;
  fout[idx * 3 + 2] = v2;
  const float step = 2.0f / 63.0f;
  dx[idx] = (-1.f + r * step) - v0 / 10.0f;
  dy[idx] = (-1.f + q * step) - v1 / 10.0f;
  dz[idx] = (-1.f + p * step) - v2 / 10.0f;
}

// ---------------- convolution kernels ----------------
#define STAGE_TILE(SRCPTR)                                                        \
  __syncthreads();                                                                \
  for (int s = threadIdx.x; s < 600; s += 256) {                                  \
    int lz = s / 100; int r2 = s - lz * 100; int ly = r2 / 10; int lx = r2 - ly * 10; \
    int gz = d0 + lz - 1, gy = h0 + ly - 1, gx = w0 + lx - 1;                     \
    float val = 0.f;                                                              \
    if ((unsigned)gz < 64u && (unsigned)gy < 64u && (unsigned)gx < 64u)           \
      val = (SRCPTR)[(gz << 12) + (gy << 6) + gx];                                \
    sh[s] = val;                                                                  \
  }                                                                               \
  __syncthreads();

__global__ __launch_bounds__(256) void conv1_kernel(const float* __restrict__ zin,
                                                    const float* __restrict__ img,
                                                    const float* __restrict__ tgt,
                                                    const float* __restrict__ wt,
                                                    float* __restrict__ x1) {
  __shared__ float sh[600];
  int tx = threadIdx.x & 7, ty = (threadIdx.x >> 3) & 7, tz = threadIdx.x >> 6;
  int w0 = blockIdx.x * 8, h0 = blockIdx.y * 8, d0 = blockIdx.z * 4;
  float acc[50];
#pragma unroll
  for (int o = 0; o < 50; ++o) acc[o] = 0.f;
  for (int ci = 0; ci < 3; ++ci) {
    const float* src = (ci == 0) ? zin : (ci == 1 ? img : tgt);
    STAGE_TILE(src)
    const float* wci = wt + ci * 27 * 52;
#pragma unroll
    for (int kd = 0; kd < 3; ++kd)
#pragma unroll
      for (int kh = 0; kh < 3; ++kh)
#pragma unroll
        for (int kw = 0; kw < 3; ++kw) {
          float xv = sh[(tz + kd) * 100 + (ty + kh) * 10 + (tx + kw)];
          const float* wrow = wci + ((kd * 3 + kh) * 3 + kw) * 52;
#pragma unroll
          for (int o = 0; o < 50; ++o) acc[o] = fmaf(xv, wrow[o], acc[o]);
        }
  }
  int idx = ((d0 + tz) << 12) + ((h0 + ty) << 6) + (w0 + tx);
#pragma unroll
  for (int o = 0; o < 50; ++o) {
    float v = acc[o];
    x1[(size_t)o * NV + idx] = (v >= 0.f) ? v : 0.01f * v;
  }
}

__global__ __launch_bounds__(256) void conv2_kernel(const float* __restrict__ x1,
                                                    const float* __restrict__ wt,
                                                    float* __restrict__ x2) {
  __shared__ float sh[600];
  int tx = threadIdx.x & 7, ty = (threadIdx.x >> 3) & 7, tz = threadIdx.x >> 6;
  int w0 = blockIdx.x * 8, h0 = blockIdx.y * 8, d0 = blockIdx.z * 4;
  float acc[50];
#pragma unroll
  for (int o = 0; o < 50; ++o) acc[o] = 0.f;
  for (int ci = 0; ci < 50; ++ci) {
    const float* src = x1 + (size_t)ci * NV;
    STAGE_TILE(src)
    const float* wci = wt + ci * 27 * 52;
#pragma unroll
    for (int kd = 0; kd < 3; ++kd)
#pragma unroll
      for (int kh = 0; kh < 3; ++kh)
#pragma unroll
        for (int kw = 0; kw < 3; ++kw) {
          float xv = sh[(tz + kd) * 100 + (ty + kh) * 10 + (tx + kw)];
          const float* wrow = wci + ((kd * 3 + kh) * 3 + kw) * 52;
#pragma unroll
          for (int o = 0; o < 50; ++o) acc[o] = fmaf(xv, wrow[o], acc[o]);
        }
  }
  int idx = ((d0 + tz) << 12) + ((h0 + ty) << 6) + (w0 + tx);
#pragma unroll
  for (int o = 0; o < 50; ++o) {
    float v = acc[o];
    x2[(size_t)o * NV + idx] = (v >= 0.f) ? v : 0.01f * v;
  }
}

// conv3 (50 -> 1) fused with residual update and residuals[i+1] output
__global__ __launch_bounds__(256) void conv3_kernel(const float* __restrict__ x2,
                                                    const float* __restrict__ w3,
                                                    float* __restrict__ residual,
                                                    float* __restrict__ resOut) {
  __shared__ float sh[600];
  int tx = threadIdx.x & 7, ty = (threadIdx.x >> 3) & 7, tz = threadIdx.x >> 6;
  int w0 = blockIdx.x * 8, h0 = blockIdx.y * 8, d0 = blockIdx.z * 4;
  float acc = 0.f;
  for (int ci = 0; ci < 50; ++ci) {
    const float* src = x2 + (size_t)ci * NV;
    STAGE_TILE(src)
    const float* wr = w3 + ci * 27;
#pragma unroll
    for (int kd = 0; kd < 3; ++kd)
#pragma unroll
      for (int kh = 0; kh < 3; ++kh)
#pragma unroll
        for (int kw = 0; kw < 3; ++kw) {
          float xv = sh[(tz + kd) * 100 + (ty + kh) * 10 + (tx + kw)];
          acc = fmaf(xv, wr[(kd * 3 + kh) * 3 + kw], acc);
        }
  }
  int idx = ((d0 + tz) << 12) + ((h0 + ty) << 6) + (w0 + tx);
  float nr = residual[idx] + acc / 10.0f;
  residual[idx] = nr;
  resOut[idx] = nr;
}

// ---------------- res_def warp + add residual ----------------
__global__ void resdef_kernel(const float* __restrict__ rdOld, const float* __restrict__ dx,
                              const float* __restrict__ dy, const float* __restrict__ dz,
                              const float* __restrict__ residual, float* __restrict__ rdNew,
                              int doSample) {
  int idx = blockIdx.x * 256 + threadIdx.x;
  float val = 0.f;
  if (doSample) {
    int id[8]; float wt[8];
    tl_make(dx[idx], dy[idx], dz[idx], 1, 64, 4096, id, wt);
    val = tl_apply(rdOld, id, wt);
  }
  rdNew[idx] = val + residual[idx];
}

// ---------------- phi warp (transposed layout semantics of the reference) ----------------
__global__ void phi_warp_kernel(const float* __restrict__ v, const float* __restrict__ phiOld,
                                float* __restrict__ phiNew) {
  int idx = blockIdx.x * 256 + threadIdx.x;
  int d = idx >> 12, h = (idx >> 6) & 63, w = idx & 63;
  const float step = 2.0f / 63.0f;
  // def(w,h,d): x uses lin[d], y lin[h], z lin[w]; v read coalesced at (d,h,w)
  float gx = (-1.f + d * step) - v[idx] / 10.0f;
  float gy = (-1.f + h * step) - v[NV + idx] / 10.0f;
  float gz = (-1.f + w * step) - v[2 * NV + idx] / 10.0f;
  int id[8]; float wt[8];
  // gather phiOld[xi, yi, zi]: x stride 4096, y stride 64, z stride 1
  tl_make(gx, gy, gz, 4096, 64, 1, id, wt);
  phiNew[idx]          = tl_apply(phiOld, id, wt);
  phiNew[NV + idx]     = tl_apply(phiOld + NV, id, wt);
  phiNew[2 * NV + idx] = tl_apply(phiOld + 2 * NV, id, wt);
}

// ---------------- image update (source & seg sampling share coords) ----------------
__global__ void image_kernel(const float* __restrict__ src, const float* __restrict__ seg,
                             const float* __restrict__ phi, const float* __restrict__ rd,
                             float* __restrict__ image) {
  int idx = blockIdx.x * 256 + threadIdx.x;
  float gx = phi[idx], gy = phi[NV + idx], gz = phi[2 * NV + idx];
  int id[8]; float wt[8];
  tl_make(gx, gy, gz, 1, 64, 4096, id, wt);
  float sval = tl_apply(src, id, wt);
  float mval = tl_apply(seg, id, wt);
  image[idx] = sval + rd[idx] * 4.0e-05f * mval;   // MU^2/L = 0.02^2/10
}

// ---------------- weight transposes: [o][ci][t] -> [ci][t][o pad 52] ----------------
__global__ void wt1_kernel(const float* __restrict__ W1, float* __restrict__ wt1) {
  int gid = blockIdx.x * 256 + threadIdx.x;
  if (gid >= 10 * 50 * 3 * 27) return;
  int t = gid % 27; int rest = gid / 27;
  int ci = rest % 3; rest /= 3;
  int o = rest % 50; int i = rest / 50;
  wt1[(((size_t)i * 3 + ci) * 27 + t) * 52 + o] = W1[gid];
}

__global__ void wt2_kernel(const float* __restrict__ W2, float* __restrict__ wt2) {
  int gid = blockIdx.x * 256 + threadIdx.x;
  if (gid >= 10 * 50 * 50 * 27) return;
  int t = gid % 27; int rest = gid / 27;
  int ci = rest % 50; rest /= 50;
  int o = rest % 50; int i = rest / 50;
  wt2[(((size_t)i * 50 + ci) * 27 + t) * 52 + o] = W2[gid];
}

// ---------------- final copy ----------------
__global__ void final_copy(const float* __restrict__ image, const float* __restrict__ rd,
                           float* __restrict__ outImg, float* __restrict__ outRd) {
  int idx = blockIdx.x * 256 + threadIdx.x;
  outImg[idx] = image[idx];
  outRd[idx] = rd[idx];
}

extern "C" void kernel_launch(void* const* d_in, const int* in_sizes, int n_in,
                              void* d_out, int out_size, void* d_ws, size_t ws_size,
                              hipStream_t stream) {
  const float* src = (const float*)d_in[0];
  const float* tgt = (const float*)d_in[1];
  const float* seg = (const float*)d_in[2];
  const float* z0  = (const float*)d_in[3];
  const float* W1  = (const float*)d_in[4];
  const float* W2  = (const float*)d_in[5];
  const float* W3  = (const float*)d_in[6];
  float* out = (float*)d_out;
  float* ws = (float*)d_ws;

  const size_t N = NV;
  float* residual = ws;
  float* image    = ws + N;
  float* rdb[2]   = { ws + 2 * N, ws + 3 * N };
  float* phib[2]  = { ws + 4 * N, ws + 7 * N };   // 3 planes each
  float* vbuf     = ws + 10 * N;                   // 3 planes
  float* t1       = ws + 13 * N;
  float* t2       = ws + 16 * N;
  float* dxb      = ws + 19 * N;
  float* dyb      = ws + 20 * N;
  float* dzb      = ws + 21 * N;
  float* x1       = ws + 22 * N;                   // 50 planes
  float* x2       = ws + 72 * N;                   // 50 planes
  float* wt1      = ws + 122 * N;                  // 42120
  float* wt2      = wt1 + 10 * 3 * 27 * 52;        // 702000

  size_t needed = (122 * N + 10 * 3 * 27 * 52 + 10 * 50 * 27 * 52) * sizeof(float);
  if (ws_size < needed) return;   // workspace too small — bail safely

  float* out_image  = out;
  float* out_fields = out + N;            // 30N
  float* out_grads  = out + 31 * N;       // 30N
  float* out_resid  = out + 61 * N;       // 11N
  float* out_rd     = out + 72 * N;

  dim3 blk(256);
  dim3 grdN((unsigned)(N / 256));
  dim3 grd3((unsigned)(N / 256), 3);
  dim3 cgrd(8, 8, 16);

  init_kernel<<<grdN, blk, 0, stream>>>(src, z0, residual, image, rdb[0], phib[0], out_resid);
  wt1_kernel<<<(10 * 50 * 3 * 27 + 255) / 256, blk, 0, stream>>>(W1, wt1);
  wt2_kernel<<<(10 * 50 * 50 * 27 + 255) / 256, blk, 0, stream>>>(W2, wt2);

  int rc = 0, pc = 0;
  for (int i = 0; i < 10; ++i) {
    float* gout = out_grads + (size_t)i * 3 * N;
    grad_kernel<<<grdN, blk, 0, stream>>>(image, gout);

    smooth_d_fused<<<grd3, blk, 0, stream>>>(residual, gout, t1);
    smooth_axis<6><<<grd3, blk, 0, stream>>>(t1, t2);
    smooth_axis<0><<<grd3, blk, 0, stream>>>(t2, vbuf);

    field_def_kernel<<<grdN, blk, 0, stream>>>(vbuf, out_fields + (size_t)i * 3 * N,
                                               dxb, dyb, dzb);

    conv1_kernel<<<cgrd, blk, 0, stream>>>(residual, image, tgt, wt1 + (size_t)i * 3 * 27 * 52, x1);
    conv2_kernel<<<cgrd, blk, 0, stream>>>(x1, wt2 + (size_t)i * 50 * 27 * 52, x2);
    conv3_kernel<<<cgrd, blk, 0, stream>>>(x2, W3 + (size_t)i * 1350, residual,
                                           out_resid + (size_t)(i + 1) * N);

    resdef_kernel<<<grdN, blk, 0, stream>>>(rdb[rc], dxb, dyb, dzb, residual, rdb[1 - rc],
                                            i > 0 ? 1 : 0);
    rc = 1 - rc;

    phi_warp_kernel<<<grdN, blk, 0, stream>>>(vbuf, phib[pc], phib[1 - pc]);
    pc = 1 - pc;

    image_kernel<<<grdN, blk, 0, stream>>>(src, seg, phib[pc], rdb[rc], image);
  }

  final_copy<<<grdN, blk, 0, stream>>>(image, rdb[rc], out_image, out_rd);
}